// Round 1
// baseline (161.452 us; speedup 1.0000x reference)
//
#include <hip/hip_runtime.h>

typedef __attribute__((ext_vector_type(8))) short short8;
typedef __attribute__((ext_vector_type(8))) __bf16 bf16x8;
typedef __attribute__((ext_vector_type(4))) float f32x4;

#define DEV __device__ __forceinline__

DEV unsigned short f2bf(float f) {
    unsigned int u = __float_as_uint(f);
    return (unsigned short)((u + 0x7FFFu + ((u >> 16) & 1u)) >> 16);
}
DEV float bf2f(unsigned short s) { return __uint_as_float(((unsigned int)s) << 16); }
DEV bf16x8 asbf(short8 v) { return __builtin_bit_cast(bf16x8, v); }

// ---------------- prep kernels ----------------

// feat (4096x512 f32) -> bf16, 8 elems/thread
__global__ __launch_bounds__(256) void k_feat(const float* __restrict__ feat,
                                              unsigned short* __restrict__ featb) {
    int i = blockIdx.x * 256 + threadIdx.x;   // 0..262143
    const float4* f4 = (const float4*)feat + (size_t)i * 2;
    float4 a = f4[0], c = f4[1];
    short8 o;
    o[0] = (short)f2bf(a.x); o[1] = (short)f2bf(a.y);
    o[2] = (short)f2bf(a.z); o[3] = (short)f2bf(a.w);
    o[4] = (short)f2bf(c.x); o[5] = (short)f2bf(c.y);
    o[6] = (short)f2bf(c.z); o[7] = (short)f2bf(c.w);
    ((short8*)featb)[i] = o;
}

// pack weights (q pre-scaled), biases, pe table (transposed [h][4096], f32)
__global__ __launch_bounds__(256) void k_pack(const float* __restrict__ qw, const float* __restrict__ qb,
                                              const float* __restrict__ kvw, const float* __restrict__ kvb,
                                              const float* __restrict__ pew, const float* __restrict__ peb,
                                              const float* __restrict__ pret, const float* __restrict__ projw,
                                              unsigned short* __restrict__ wqkv, float* __restrict__ bqkv,
                                              unsigned short* __restrict__ projwb, float* __restrict__ peT) {
    const float scale = 0.17677669529663687f; // 1/sqrt(32)
    int i = blockIdx.x * 256 + threadIdx.x;
    if (i < 786432) {                       // wqkv: [1536][512]
        int o = i >> 9, k = i & 511;
        float v = (o < 512) ? qw[(o << 9) + k] * scale : kvw[((o - 512) << 9) + k];
        wqkv[i] = f2bf(v);
    } else if (i < 786432 + 262144) {       // projwb: [512][512]
        int j = i - 786432;
        projwb[j] = f2bf(projw[j]);
    } else if (i < 786432 + 262144 + 1536) { // bqkv
        int o = i - (786432 + 262144);
        bqkv[o] = (o < 512) ? qb[o] * scale : kvb[o - 512];
    } else if (i < 786432 + 262144 + 1536 + 65536) { // peT[h][4096]
        int j = i - (786432 + 262144 + 1536);
        int h = j >> 12, t = j & 4095;
        float s = peb[h];
#pragma unroll
        for (int u = 0; u < 5; u++) s += pret[t * 5 + u] * pew[h * 5 + u];
        peT[(h << 12) + t] = s;
    }
}

// ---------------- QKV GEMM ----------------
// C[4096,1536] = featb @ wqkv^T + bqkv, scattered into Qh/Kh (b,h,n,32) and Vt (b,h,32,n)
__global__ __launch_bounds__(256) void k_qkv(const unsigned short* __restrict__ A,
                                             const unsigned short* __restrict__ Bw,
                                             const float* __restrict__ bias,
                                             unsigned short* __restrict__ Qh,
                                             unsigned short* __restrict__ Kh,
                                             unsigned short* __restrict__ Vt) {
    __shared__ __align__(16) unsigned short As[128][72];
    __shared__ __align__(16) unsigned short Bs[64][72];
    int tid = threadIdx.x, lane = tid & 63, wid = tid >> 6;
    int m0 = blockIdx.y * 128, n0 = blockIdx.x * 64;
    int wm = wid >> 1, wn = wid & 1;
    f32x4 acc[4][2] = {};

    for (int k0 = 0; k0 < 512; k0 += 64) {
        {   // stage A: 128x64
            int row = tid >> 1, cs = (tid & 1) * 32;
            const short8* src = (const short8*)(A + (size_t)(m0 + row) * 512 + k0 + cs);
            short8* dst = (short8*)(&As[row][cs]);
            dst[0] = src[0]; dst[1] = src[1]; dst[2] = src[2]; dst[3] = src[3];
        }
        {   // stage B: 64x64
            int row = tid >> 2, cs = (tid & 3) * 16;
            const short8* src = (const short8*)(Bw + (size_t)(n0 + row) * 512 + k0 + cs);
            short8* dst = (short8*)(&Bs[row][cs]);
            dst[0] = src[0]; dst[1] = src[1];
        }
        __syncthreads();
#pragma unroll
        for (int kk = 0; kk < 64; kk += 32) {
            short8 a[4], b[2];
#pragma unroll
            for (int m = 0; m < 4; m++)
                a[m] = *(const short8*)(&As[wm * 64 + m * 16 + (lane & 15)][kk + ((lane >> 4) << 3)]);
#pragma unroll
            for (int n = 0; n < 2; n++)
                b[n] = *(const short8*)(&Bs[wn * 32 + n * 16 + (lane & 15)][kk + ((lane >> 4) << 3)]);
#pragma unroll
            for (int m = 0; m < 4; m++) {
#pragma unroll
                for (int n = 0; n < 2; n++)
                    acc[m][n] = __builtin_amdgcn_mfma_f32_16x16x32_bf16(asbf(a[m]), asbf(b[n]), acc[m][n], 0, 0, 0);
            }
        }
        __syncthreads();
    }
    // epilogue: scatter
#pragma unroll
    for (int m = 0; m < 4; m++) {
#pragma unroll
        for (int n = 0; n < 2; n++) {
            int col = n0 + wn * 32 + n * 16 + (lane & 15);
            float bv = bias[col];
#pragma unroll
            for (int r = 0; r < 4; r++) {
                int row = m0 + wm * 64 + m * 16 + ((lane >> 4) << 2) + r;
                float v = acc[m][n][r] + bv;
                unsigned short bb = f2bf(v);
                int batch = row >> 10, nn = row & 1023;
                if (col < 512) {
                    int h = col >> 5, d = col & 31;
                    Qh[((((batch << 4) + h) << 10) + nn) * 32 + d] = bb;
                } else {
                    int oo = col - 512, h = oo >> 6, rem = oo & 63;
                    if (rem < 32)
                        Kh[((((batch << 4) + h) << 10) + nn) * 32 + rem] = bb;
                    else
                        Vt[(((batch << 4) + h) * 32 + (rem - 32)) * 1024 + nn] = bb;
                }
            }
        }
    }
}

// ---------------- fused attention ----------------
// one block per (qtile of 64, h, b); 4 waves, each owns 16 q-rows
__global__ __launch_bounds__(256) void k_attn(const unsigned short* __restrict__ Qh,
                                              const unsigned short* __restrict__ Kh,
                                              const unsigned short* __restrict__ Vt,
                                              const int* __restrict__ pe_idx,
                                              const float* __restrict__ peT,
                                              const float* __restrict__ blank_k,
                                              const float* __restrict__ blank_v,
                                              unsigned short* __restrict__ attnO) {
    __shared__ __align__(16) unsigned short Ps[4][16][72];
    int tid = threadIdx.x, lane = tid & 63, wid = tid >> 6;
    int qt = blockIdx.x, h = blockIdx.y, b = blockIdx.z;
    int q0 = qt * 64;
    int bh = (b << 4) + h;

    // Q fragment (held all kernel): row = lane&15 within strip, k(d) = (lane>>4)*8+t
    int qrow = q0 + wid * 16 + (lane & 15);
    short8 qf = *(const short8*)(Qh + ((size_t)((bh << 10) + qrow)) * 32 + ((lane >> 4) << 3));

    // blank logit per row via in-register dot + shuffles
    float dotp = 0.f;
    {
        const float* bk = blank_k + h * 32 + ((lane >> 4) << 3);
#pragma unroll
        for (int t = 0; t < 8; t++) dotp += bf2f((unsigned short)qf[t]) * bk[t];
        dotp += __shfl_xor(dotp, 16, 64);
        dotp += __shfl_xor(dotp, 32, 64);
    }
    float lb[4], m_run[4], l_run[4];
#pragma unroll
    for (int r = 0; r < 4; r++) {
        lb[r] = __shfl(dotp, ((lane >> 4) << 2) + r, 64);
        m_run[r] = lb[r];
        l_run[r] = 1.0f;
    }
    f32x4 acc[2] = {};
    const f32x4 zero = {};

    for (int kt = 0; kt < 16; kt++) {
        int k0 = kt * 64;
        short8 kf[4];
#pragma unroll
        for (int cb = 0; cb < 4; cb++)
            kf[cb] = *(const short8*)(Kh + ((size_t)((bh << 10) + k0 + cb * 16 + (lane & 15))) * 32 + ((lane >> 4) << 3));
        f32x4 s[4];
#pragma unroll
        for (int cb = 0; cb < 4; cb++)
            s[cb] = __builtin_amdgcn_mfma_f32_16x16x32_bf16(asbf(qf), asbf(kf[cb]), zero, 0, 0, 0);

        // add positional term (gathered); S layout: col(key)=lane&15, row=(lane>>4)*4+r
#pragma unroll
        for (int r = 0; r < 4; r++) {
            int qg = q0 + wid * 16 + ((lane >> 4) << 2) + r;
            const int* pi = pe_idx + ((size_t)((b << 10) + qg)) * 1024 + k0 + (lane & 15);
#pragma unroll
            for (int cb = 0; cb < 4; cb++) {
                int idx = pi[cb * 16];
                s[cb][r] += peT[(h << 12) + idx];
            }
        }
        // online softmax
        float mt[4];
#pragma unroll
        for (int r = 0; r < 4; r++) {
            float v = fmaxf(fmaxf(s[0][r], s[1][r]), fmaxf(s[2][r], s[3][r]));
#pragma unroll
            for (int off = 1; off < 16; off <<= 1) v = fmaxf(v, __shfl_xor(v, off, 64));
            mt[r] = v;
        }
#pragma unroll
        for (int r = 0; r < 4; r++) {
            float mn = fmaxf(m_run[r], mt[r]);
            float fac = __expf(m_run[r] - mn);
            m_run[r] = mn;
            float sum = 0.f;
#pragma unroll
            for (int cb = 0; cb < 4; cb++) {
                float p = __expf(s[cb][r] - mn);
                s[cb][r] = p;
                sum += p;
            }
#pragma unroll
            for (int off = 1; off < 16; off <<= 1) sum += __shfl_xor(sum, off, 64);
            l_run[r] = l_run[r] * fac + sum;
            acc[0][r] *= fac;
            acc[1][r] *= fac;
        }
        // P -> LDS (per-wave private region), then read back as A-fragment
#pragma unroll
        for (int cb = 0; cb < 4; cb++) {
#pragma unroll
            for (int r = 0; r < 4; r++)
                Ps[wid][((lane >> 4) << 2) + r][cb * 16 + (lane & 15)] = f2bf(s[cb][r]);
        }
        __syncthreads();
        short8 pf[2];
#pragma unroll
        for (int kb = 0; kb < 2; kb++)
            pf[kb] = *(const short8*)(&Ps[wid][lane & 15][kb * 32 + ((lane >> 4) << 3)]);
#pragma unroll
        for (int db = 0; db < 2; db++) {
#pragma unroll
            for (int kb = 0; kb < 2; kb++) {
                short8 vf = *(const short8*)(Vt + ((size_t)(bh * 32 + db * 16 + (lane & 15))) * 1024 + k0 + kb * 32 + ((lane >> 4) << 3));
                acc[db] = __builtin_amdgcn_mfma_f32_16x16x32_bf16(asbf(pf[kb]), asbf(vf), acc[db], 0, 0, 0);
            }
        }
        __syncthreads();
    }
    // epilogue
#pragma unroll
    for (int r = 0; r < 4; r++) {
        float inv = 1.0f / l_run[r];
        float bw = __expf(lb[r] - m_run[r]) * inv;
        int qg = q0 + wid * 16 + ((lane >> 4) << 2) + r;
#pragma unroll
        for (int db = 0; db < 2; db++) {
            int d = db * 16 + (lane & 15);
            float ov = acc[db][r] * inv + bw * blank_v[h * 32 + d];
            attnO[((size_t)((b << 10) + qg)) * 512 + h * 32 + d] = f2bf(ov);
        }
    }
}

// ---------------- final projection GEMM ----------------
__global__ __launch_bounds__(256) void k_proj(const unsigned short* __restrict__ A,
                                              const unsigned short* __restrict__ Bw,
                                              const float* __restrict__ bias,
                                              float* __restrict__ out) {
    __shared__ __align__(16) unsigned short As[128][72];
    __shared__ __align__(16) unsigned short Bs[64][72];
    int tid = threadIdx.x, lane = tid & 63, wid = tid >> 6;
    int m0 = blockIdx.y * 128, n0 = blockIdx.x * 64;
    int wm = wid >> 1, wn = wid & 1;
    f32x4 acc[4][2] = {};

    for (int k0 = 0; k0 < 512; k0 += 64) {
        {
            int row = tid >> 1, cs = (tid & 1) * 32;
            const short8* src = (const short8*)(A + (size_t)(m0 + row) * 512 + k0 + cs);
            short8* dst = (short8*)(&As[row][cs]);
            dst[0] = src[0]; dst[1] = src[1]; dst[2] = src[2]; dst[3] = src[3];
        }
        {
            int row = tid >> 2, cs = (tid & 3) * 16;
            const short8* src = (const short8*)(Bw + (size_t)(n0 + row) * 512 + k0 + cs);
            short8* dst = (short8*)(&Bs[row][cs]);
            dst[0] = src[0]; dst[1] = src[1];
        }
        __syncthreads();
#pragma unroll
        for (int kk = 0; kk < 64; kk += 32) {
            short8 a[4], b[2];
#pragma unroll
            for (int m = 0; m < 4; m++)
                a[m] = *(const short8*)(&As[wm * 64 + m * 16 + (lane & 15)][kk + ((lane >> 4) << 3)]);
#pragma unroll
            for (int n = 0; n < 2; n++)
                b[n] = *(const short8*)(&Bs[wn * 32 + n * 16 + (lane & 15)][kk + ((lane >> 4) << 3)]);
#pragma unroll
            for (int m = 0; m < 4; m++) {
#pragma unroll
                for (int n = 0; n < 2; n++)
                    acc[m][n] = __builtin_amdgcn_mfma_f32_16x16x32_bf16(asbf(a[m]), asbf(b[n]), acc[m][n], 0, 0, 0);
            }
        }
        __syncthreads();
    }
#pragma unroll
    for (int m = 0; m < 4; m++) {
#pragma unroll
        for (int n = 0; n < 2; n++) {
            int col = n0 + wn * 32 + n * 16 + (lane & 15);
            float bv = bias[col];
#pragma unroll
            for (int r = 0; r < 4; r++) {
                int row = m0 + wm * 64 + m * 16 + ((lane >> 4) << 2) + r;
                out[(size_t)row * 512 + col] = acc[m][n][r] + bv;
            }
        }
    }
}

extern "C" void kernel_launch(void* const* d_in, const int* in_sizes, int n_in,
                              void* d_out, int out_size, void* d_ws, size_t ws_size,
                              hipStream_t stream) {
    const float* feat    = (const float*)d_in[0];
    const int*   pe_idx  = (const int*)d_in[3];
    const float* pret    = (const float*)d_in[5];
    const float* qw      = (const float*)d_in[6];
    const float* qb      = (const float*)d_in[7];
    const float* kvw     = (const float*)d_in[8];
    const float* kvb     = (const float*)d_in[9];
    const float* pew     = (const float*)d_in[10];
    const float* peb     = (const float*)d_in[11];
    const float* blank_k = (const float*)d_in[12];
    const float* blank_v = (const float*)d_in[13];
    const float* projw   = (const float*)d_in[14];
    const float* projb   = (const float*)d_in[15];

    char* ws = (char*)d_ws;
    unsigned short* featb  = (unsigned short*)(ws);
    unsigned short* wqkv   = (unsigned short*)(ws + 4194304);
    unsigned short* projwb = (unsigned short*)(ws + 5767168);
    float*          bqkv   = (float*)(ws + 6291456);
    float*          peT    = (float*)(ws + 6297600);
    unsigned short* Qh     = (unsigned short*)(ws + 6559744);
    unsigned short* Kh     = (unsigned short*)(ws + 10754048);
    unsigned short* Vt     = (unsigned short*)(ws + 14948352);
    unsigned short* attnO  = (unsigned short*)(ws + 19142656);

    k_feat<<<dim3(1024), dim3(256), 0, stream>>>(feat, featb);
    k_pack<<<dim3(4358), dim3(256), 0, stream>>>(qw, qb, kvw, kvb, pew, peb, pret, projw,
                                                 wqkv, bqkv, projwb, peT);
    k_qkv<<<dim3(24, 32), dim3(256), 0, stream>>>(featb, wqkv, bqkv, Qh, Kh, Vt);
    k_attn<<<dim3(16, 16, 4), dim3(256), 0, stream>>>(Qh, Kh, Vt, pe_idx, peT, blank_k, blank_v, attnO);
    k_proj<<<dim3(8, 32), dim3(256), 0, stream>>>(attnO, projwb, projb, (float*)d_out);
}

// Round 2
// 105.906 us; speedup vs baseline: 1.5245x; 1.5245x over previous
//
#include <hip/hip_runtime.h>
#include <hip/hip_fp16.h>

typedef __attribute__((ext_vector_type(8))) short short8;
typedef __attribute__((ext_vector_type(8))) __bf16 bf16x8;
typedef __attribute__((ext_vector_type(4))) float f32x4;

#define DEV __device__ __forceinline__

DEV unsigned short f2bf(float f) {
    unsigned int u = __float_as_uint(f);
    return (unsigned short)((u + 0x7FFFu + ((u >> 16) & 1u)) >> 16);
}
DEV float bf2f(unsigned short s) { return __uint_as_float(((unsigned int)s) << 16); }
DEV bf16x8 asbf(short8 v) { return __builtin_bit_cast(bf16x8, v); }

DEV uint4 perm4(uint4 x, int v) {   // out[i] = x[i^v]
    uint4 r = x;
    if (v & 1) { unsigned t = r.x; r.x = r.y; r.y = t; t = r.z; r.z = r.w; r.w = t; }
    if (v & 2) { unsigned t = r.x; r.x = r.z; r.z = t; t = r.y; r.y = r.w; r.w = t; }
    return r;
}

// ---------------- prep kernels ----------------

__global__ __launch_bounds__(256) void k_feat(const float* __restrict__ feat,
                                              unsigned short* __restrict__ featb) {
    int i = blockIdx.x * 256 + threadIdx.x;
    const float4* f4 = (const float4*)feat + (size_t)i * 2;
    float4 a = f4[0], c = f4[1];
    short8 o;
    o[0] = (short)f2bf(a.x); o[1] = (short)f2bf(a.y);
    o[2] = (short)f2bf(a.z); o[3] = (short)f2bf(a.w);
    o[4] = (short)f2bf(c.x); o[5] = (short)f2bf(c.y);
    o[6] = (short)f2bf(c.z); o[7] = (short)f2bf(c.w);
    ((short8*)featb)[i] = o;
}

__global__ __launch_bounds__(256) void k_pack(const float* __restrict__ qw, const float* __restrict__ qb,
                                              const float* __restrict__ kvw, const float* __restrict__ kvb,
                                              const float* __restrict__ pew, const float* __restrict__ peb,
                                              const float* __restrict__ pret, const float* __restrict__ projw,
                                              unsigned short* __restrict__ wqkv, float* __restrict__ bqkv,
                                              unsigned short* __restrict__ projwb, unsigned short* __restrict__ peAll) {
    const float scale = 0.17677669529663687f; // 1/sqrt(32)
    int i = blockIdx.x * 256 + threadIdx.x;
    if (i < 786432) {
        int o = i >> 9, k = i & 511;
        float v = (o < 512) ? qw[(o << 9) + k] * scale : kvw[((o - 512) << 9) + k];
        wqkv[i] = f2bf(v);
    } else if (i < 786432 + 262144) {
        int j = i - 786432;
        projwb[j] = f2bf(projw[j]);
    } else if (i < 786432 + 262144 + 1536) {
        int o = i - (786432 + 262144);
        bqkv[o] = (o < 512) ? qb[o] * scale : kvb[o - 512];
    } else if (i < 786432 + 262144 + 1536 + 65536) { // peAll[t][h] f16
        int j = i - (786432 + 262144 + 1536);
        int t = j >> 4, h = j & 15;
        float s = peb[h];
#pragma unroll
        for (int u = 0; u < 5; u++) s += pret[t * 5 + u] * pew[h * 5 + u];
        peAll[j] = __builtin_bit_cast(unsigned short, __float2half(s));
    }
}

// ---------------- QKV GEMM ----------------
__global__ __launch_bounds__(256) void k_qkv(const unsigned short* __restrict__ A,
                                             const unsigned short* __restrict__ Bw,
                                             const float* __restrict__ bias,
                                             unsigned short* __restrict__ Qh,
                                             unsigned short* __restrict__ Kh,
                                             unsigned short* __restrict__ Vt) {
    __shared__ __align__(16) unsigned short As[128][72];
    __shared__ __align__(16) unsigned short Bs[64][72];
    int tid = threadIdx.x, lane = tid & 63, wid = tid >> 6;
    int m0 = blockIdx.y * 128, n0 = blockIdx.x * 64;
    int wm = wid >> 1, wn = wid & 1;
    f32x4 acc[4][2] = {};

    for (int k0 = 0; k0 < 512; k0 += 64) {
        {
            int row = tid >> 1, cs = (tid & 1) * 32;
            const short8* src = (const short8*)(A + (size_t)(m0 + row) * 512 + k0 + cs);
            short8* dst = (short8*)(&As[row][cs]);
            dst[0] = src[0]; dst[1] = src[1]; dst[2] = src[2]; dst[3] = src[3];
        }
        {
            int row = tid >> 2, cs = (tid & 3) * 16;
            const short8* src = (const short8*)(Bw + (size_t)(n0 + row) * 512 + k0 + cs);
            short8* dst = (short8*)(&Bs[row][cs]);
            dst[0] = src[0]; dst[1] = src[1];
        }
        __syncthreads();
#pragma unroll
        for (int kk = 0; kk < 64; kk += 32) {
            short8 a[4], b[2];
#pragma unroll
            for (int m = 0; m < 4; m++)
                a[m] = *(const short8*)(&As[wm * 64 + m * 16 + (lane & 15)][kk + ((lane >> 4) << 3)]);
#pragma unroll
            for (int n = 0; n < 2; n++)
                b[n] = *(const short8*)(&Bs[wn * 32 + n * 16 + (lane & 15)][kk + ((lane >> 4) << 3)]);
#pragma unroll
            for (int m = 0; m < 4; m++) {
#pragma unroll
                for (int n = 0; n < 2; n++)
                    acc[m][n] = __builtin_amdgcn_mfma_f32_16x16x32_bf16(asbf(a[m]), asbf(b[n]), acc[m][n], 0, 0, 0);
            }
        }
        __syncthreads();
    }
#pragma unroll
    for (int m = 0; m < 4; m++) {
#pragma unroll
        for (int n = 0; n < 2; n++) {
            int col = n0 + wn * 32 + n * 16 + (lane & 15);
            float bv = bias[col];
#pragma unroll
            for (int r = 0; r < 4; r++) {
                int row = m0 + wm * 64 + m * 16 + ((lane >> 4) << 2) + r;
                float v = acc[m][n][r] + bv;
                unsigned short bb = f2bf(v);
                int batch = row >> 10, nn = row & 1023;
                if (col < 512) {
                    int h = col >> 5, d = col & 31;
                    Qh[((((batch << 4) + h) << 10) + nn) * 32 + d] = bb;
                } else {
                    int oo = col - 512, h = oo >> 6, rem = oo & 63;
                    if (rem < 32)
                        Kh[((((batch << 4) + h) << 10) + nn) * 32 + rem] = bb;
                    else
                        Vt[(((batch << 4) + h) * 32 + (rem - 32)) * 1024 + nn] = bb;
                }
            }
        }
    }
}

// ---------------- fused attention (all 16 heads per block, k-chunked) ----------------
// grid: 256 blocks; bid -> b = bid&3 (XCD L2 locality), qt = (bid>>2)&31, kc = bid>>7
// 512 threads = 8 waves; wave w owns heads 2w, 2w+1; q-tile 32 rows; k-chunk 512
__global__ __launch_bounds__(512, 1) void k_attn(const unsigned short* __restrict__ Qh,
                                                 const unsigned short* __restrict__ Kh,
                                                 const unsigned short* __restrict__ Vt,
                                                 const int* __restrict__ pe_idx,
                                                 const unsigned short* __restrict__ peAll,
                                                 const float* __restrict__ blank_k,
                                                 float* __restrict__ partial,
                                                 float* __restrict__ ml,
                                                 float* __restrict__ lbuf) {
    __shared__ unsigned int posb[2][16384];            // 2 x 2048 els x 32B = 128 KB
    __shared__ __align__(16) unsigned short Ps[8][16][72]; // per-wave P tile (18 KB)

    int tid = threadIdx.x, lane = tid & 63, w = tid >> 6;
    int g = lane >> 4, q16 = lane & 15;
    int bid = blockIdx.x;
    int b = bid & 3, rest = bid >> 2, qt = rest & 31, kc = rest >> 5;
    int q0 = qt * 32, k_base = kc * 512;

    // gather-phase thread map
    int qg = tid & 31, kq = tid >> 5;   // q_local 0..31, k-quad 0..15
    int vperm = kq & 3;

    // Q fragments (held all kernel)
    short8 qf[2][2];
    float lb_[2][2], m_run[2][2], l_run[2][2];
#pragma unroll
    for (int hh = 0; hh < 2; hh++) {
        int bh = (b << 4) + 2 * w + hh;
#pragma unroll
        for (int s = 0; s < 2; s++) {
            int qrow = q0 + s * 16 + q16;
            qf[hh][s] = *(const short8*)(Qh + ((size_t)((bh << 10) + qrow)) * 32 + (g << 3));
            float dotp = 0.f;
            const float* bk = blank_k + (2 * w + hh) * 32 + (g << 3);
#pragma unroll
            for (int t = 0; t < 8; t++) dotp += bf2f((unsigned short)qf[hh][s][t]) * bk[t];
            dotp += __shfl_xor(dotp, 16, 64);
            dotp += __shfl_xor(dotp, 32, 64);
            lb_[hh][s] = dotp;
            m_run[hh][s] = (kc == 0) ? dotp : -1e30f;
            l_run[hh][s] = (kc == 0) ? 1.0f : 0.0f;
        }
    }
    f32x4 acc[2][2][2] = {};
    const f32x4 zero = {};

    // prologue: gather kt=0
    {
        const int* pib = pe_idx + ((size_t)((b << 10) + q0 + qg)) * 1024 + k_base + kq * 4;
        int4 idx4 = *(const int4*)pib;
        int id[4] = {idx4.x, idx4.y, idx4.z, idx4.w};
#pragma unroll
        for (int j = 0; j < 4; j++) {
            const uint4* src = (const uint4*)(peAll + ((size_t)id[j] << 4));
            uint4 a = perm4(src[0], vperm), c = perm4(src[1], vperm);
            int el = (kq * 4 + j) * 32 + qg;
            uint4* dst = (uint4*)&posb[0][el * 8];
            dst[0] = a; dst[1] = c;
        }
    }
    __syncthreads();

    for (int kt = 0; kt < 8; kt++) {
        int cur = kt & 1, nxt = cur ^ 1;
        int kg0 = k_base + kt * 64;

        // issue next-tile gathers early (regs), write to LDS late
        uint4 ga[4], gb_[4];
        if (kt < 7) {
            const int* pib = pe_idx + ((size_t)((b << 10) + q0 + qg)) * 1024 + k_base + (kt + 1) * 64 + kq * 4;
            int4 idx4 = *(const int4*)pib;
            int id[4] = {idx4.x, idx4.y, idx4.z, idx4.w};
#pragma unroll
            for (int j = 0; j < 4; j++) {
                const uint4* src = (const uint4*)(peAll + ((size_t)id[j] << 4));
                ga[j] = src[0]; gb_[j] = src[1];
            }
        }

        // K / V fragments for this tile
        short8 kf[2][4], vf[2][2][2];
#pragma unroll
        for (int hh = 0; hh < 2; hh++) {
            int bh = (b << 4) + 2 * w + hh;
#pragma unroll
            for (int cb = 0; cb < 4; cb++)
                kf[hh][cb] = *(const short8*)(Kh + ((size_t)((bh << 10) + kg0 + cb * 16 + q16)) * 32 + (g << 3));
#pragma unroll
            for (int db = 0; db < 2; db++)
#pragma unroll
                for (int kb = 0; kb < 2; kb++)
                    vf[hh][db][kb] = *(const short8*)(Vt + ((size_t)(bh * 32 + db * 16 + q16)) * 1024 + kg0 + kb * 32 + (g << 3));
        }

#pragma unroll
        for (int s = 0; s < 2; s++) {
            // pos reads: one b32 per element carries both heads of this wave
            unsigned int pw[4][4];
#pragma unroll
            for (int cb = 0; cb < 4; cb++)
#pragma unroll
                for (int r = 0; r < 4; r++) {
                    int el = (cb * 16 + g * 4 + r) * 32 + s * 16 + q16;
                    pw[cb][r] = posb[cur][el * 8 + (w & 4) + ((w & 3) ^ g)];
                }
#pragma unroll
            for (int hh = 0; hh < 2; hh++) {
                f32x4 sv[4];
#pragma unroll
                for (int cb = 0; cb < 4; cb++)
                    sv[cb] = __builtin_amdgcn_mfma_f32_16x16x32_bf16(asbf(kf[hh][cb]), asbf(qf[hh][s]), zero, 0, 0, 0);
#pragma unroll
                for (int cb = 0; cb < 4; cb++)
#pragma unroll
                    for (int r = 0; r < 4; r++) {
                        __half2 h2 = __builtin_bit_cast(__half2, pw[cb][r]);
                        sv[cb][r] += hh ? __high2float(h2) : __low2float(h2);
                    }
                // softmax (row q = q16, values spread over g)
                float mx = -1e30f;
#pragma unroll
                for (int cb = 0; cb < 4; cb++)
#pragma unroll
                    for (int r = 0; r < 4; r++) mx = fmaxf(mx, sv[cb][r]);
                mx = fmaxf(mx, __shfl_xor(mx, 16, 64));
                mx = fmaxf(mx, __shfl_xor(mx, 32, 64));
                float mn = fmaxf(m_run[hh][s], mx);
                float fac = __expf(m_run[hh][s] - mn);
                m_run[hh][s] = mn;
                float sum = 0.f;
#pragma unroll
                for (int cb = 0; cb < 4; cb++)
#pragma unroll
                    for (int r = 0; r < 4; r++) {
                        float p = __expf(sv[cb][r] - mn);
                        sv[cb][r] = p;
                        sum += p;
                    }
                sum += __shfl_xor(sum, 16, 64);
                sum += __shfl_xor(sum, 32, 64);
                l_run[hh][s] = l_run[hh][s] * fac + sum;
#pragma unroll
                for (int r = 0; r < 4; r++) {
                    float facr = __shfl(fac, g * 4 + r, 64);
                    acc[hh][s][0][r] *= facr;
                    acc[hh][s][1][r] *= facr;
                }
                // P -> LDS (wave-private), bf16
#pragma unroll
                for (int cb = 0; cb < 4; cb++) {
                    unsigned int u0 = (unsigned int)f2bf(sv[cb][0]) | ((unsigned int)f2bf(sv[cb][1]) << 16);
                    unsigned int u1 = (unsigned int)f2bf(sv[cb][2]) | ((unsigned int)f2bf(sv[cb][3]) << 16);
                    uint2 pk = {u0, u1};
                    *(uint2*)(&Ps[w][q16][cb * 16 + g * 4]) = pk;
                }
                short8 pa[2];
#pragma unroll
                for (int kb = 0; kb < 2; kb++)
                    pa[kb] = *(const short8*)(&Ps[w][q16][kb * 32 + g * 8]);
#pragma unroll
                for (int db = 0; db < 2; db++)
#pragma unroll
                    for (int kb = 0; kb < 2; kb++)
                        acc[hh][s][db] = __builtin_amdgcn_mfma_f32_16x16x32_bf16(asbf(pa[kb]), asbf(vf[hh][db][kb]), acc[hh][s][db], 0, 0, 0);
            }
        }
        if (kt < 7) {
#pragma unroll
            for (int j = 0; j < 4; j++) {
                int el = (kq * 4 + j) * 32 + qg;
                uint4* dst = (uint4*)&posb[nxt][el * 8];
                dst[0] = perm4(ga[j], vperm);
                dst[1] = perm4(gb_[j], vperm);
            }
        }
        __syncthreads();
    }

    // epilogue: partials
#pragma unroll
    for (int hh = 0; hh < 2; hh++) {
        int hcol = 2 * w + hh;
        size_t base = ((size_t)((b * 2 + kc) * 16 + hcol)) * 1024;
#pragma unroll
        for (int s = 0; s < 2; s++) {
#pragma unroll
            for (int db = 0; db < 2; db++)
#pragma unroll
                for (int r = 0; r < 4; r++) {
                    int qrow = q0 + s * 16 + g * 4 + r;
                    partial[(base + qrow) * 32 + db * 16 + q16] = acc[hh][s][db][r];
                }
            if (g == 0) {
                int qrow = q0 + s * 16 + q16;
                ml[(base + qrow) * 2 + 0] = m_run[hh][s];
                ml[(base + qrow) * 2 + 1] = l_run[hh][s];
                if (kc == 0)
                    lbuf[((size_t)((b << 4) + hcol) << 10) + qrow] = lb_[hh][s];
            }
        }
    }
}

// ---------------- combine partials + blank ----------------
__global__ __launch_bounds__(256) void k_comb(const float* __restrict__ partial,
                                              const float* __restrict__ ml,
                                              const float* __restrict__ lbuf,
                                              const float* __restrict__ blank_v,
                                              unsigned short* __restrict__ attnO) {
    int t = blockIdx.x * 256 + threadIdx.x;     // 0..2M-1
    int d = t & 31;
    int row = t >> 5;                            // (b*16+h)*1024 + q
    int b = row >> 14, h = (row >> 10) & 15, q = row & 1023;
    size_t iA = ((size_t)((b * 2 + 0) * 16 + h) << 10) + q;
    size_t iB = ((size_t)((b * 2 + 1) * 16 + h) << 10) + q;
    float mA = ml[iA * 2], lA = ml[iA * 2 + 1];
    float mB = ml[iB * 2], lB = ml[iB * 2 + 1];
    float lb = lbuf[row];
    float M = fmaxf(mA, mB);
    float eA = __expf(mA - M), eB = __expf(mB - M);
    float L = lA * eA + lB * eB;
    float val = (partial[iA * 32 + d] * eA + partial[iB * 32 + d] * eB) / L
              + __expf(lb - M) / L * blank_v[h * 32 + d];
    attnO[((size_t)((b << 10) + q)) * 512 + h * 32 + d] = f2bf(val);
}

// ---------------- final projection GEMM ----------------
__global__ __launch_bounds__(256) void k_proj(const unsigned short* __restrict__ A,
                                              const unsigned short* __restrict__ Bw,
                                              const float* __restrict__ bias,
                                              float* __restrict__ out) {
    __shared__ __align__(16) unsigned short As[128][72];
    __shared__ __align__(16) unsigned short Bs[64][72];
    int tid = threadIdx.x, lane = tid & 63, wid = tid >> 6;
    int m0 = blockIdx.y * 128, n0 = blockIdx.x * 64;
    int wm = wid >> 1, wn = wid & 1;
    f32x4 acc[4][2] = {};

    for (int k0 = 0; k0 < 512; k0 += 64) {
        {
            int row = tid >> 1, cs = (tid & 1) * 32;
            const short8* src = (const short8*)(A + (size_t)(m0 + row) * 512 + k0 + cs);
            short8* dst = (short8*)(&As[row][cs]);
            dst[0] = src[0]; dst[1] = src[1]; dst[2] = src[2]; dst[3] = src[3];
        }
        {
            int row = tid >> 2, cs = (tid & 3) * 16;
            const short8* src = (const short8*)(Bw + (size_t)(n0 + row) * 512 + k0 + cs);
            short8* dst = (short8*)(&Bs[row][cs]);
            dst[0] = src[0]; dst[1] = src[1];
        }
        __syncthreads();
#pragma unroll
        for (int kk = 0; kk < 64; kk += 32) {
            short8 a[4], b[2];
#pragma unroll
            for (int m = 0; m < 4; m++)
                a[m] = *(const short8*)(&As[wm * 64 + m * 16 + (lane & 15)][kk + ((lane >> 4) << 3)]);
#pragma unroll
            for (int n = 0; n < 2; n++)
                b[n] = *(const short8*)(&Bs[wn * 32 + n * 16 + (lane & 15)][kk + ((lane >> 4) << 3)]);
#pragma unroll
            for (int m = 0; m < 4; m++) {
#pragma unroll
                for (int n = 0; n < 2; n++)
                    acc[m][n] = __builtin_amdgcn_mfma_f32_16x16x32_bf16(asbf(a[m]), asbf(b[n]), acc[m][n], 0, 0, 0);
            }
        }
        __syncthreads();
    }
#pragma unroll
    for (int m = 0; m < 4; m++) {
#pragma unroll
        for (int n = 0; n < 2; n++) {
            int col = n0 + wn * 32 + n * 16 + (lane & 15);
            float bv = bias[col];
#pragma unroll
            for (int r = 0; r < 4; r++) {
                int row = m0 + wm * 64 + m * 16 + ((lane >> 4) << 2) + r;
                out[(size_t)row * 512 + col] = acc[m][n][r] + bv;
            }
        }
    }
}

extern "C" void kernel_launch(void* const* d_in, const int* in_sizes, int n_in,
                              void* d_out, int out_size, void* d_ws, size_t ws_size,
                              hipStream_t stream) {
    const float* feat    = (const float*)d_in[0];
    const int*   pe_idx  = (const int*)d_in[3];
    const float* pret    = (const float*)d_in[5];
    const float* qw      = (const float*)d_in[6];
    const float* qb      = (const float*)d_in[7];
    const float* kvw     = (const float*)d_in[8];
    const float* kvb     = (const float*)d_in[9];
    const float* pew     = (const float*)d_in[10];
    const float* peb     = (const float*)d_in[11];
    const float* blank_k = (const float*)d_in[12];
    const float* blank_v = (const float*)d_in[13];
    const float* projw   = (const float*)d_in[14];
    const float* projb   = (const float*)d_in[15];

    char* ws = (char*)d_ws;
    unsigned short* featb  = (unsigned short*)(ws);                  // 4 MB (reused as attnO)
    unsigned short* wqkv   = (unsigned short*)(ws + 4194304);        // 1.5 MB
    unsigned short* projwb = (unsigned short*)(ws + 5767168);        // 0.5 MB
    float*          bqkv   = (float*)(ws + 6291456);                 // 6 KB
    unsigned short* peAll  = (unsigned short*)(ws + 6297600);        // 128 KB
    unsigned short* Qh     = (unsigned short*)(ws + 6428672);        // 4 MB
    unsigned short* Kh     = (unsigned short*)(ws + 10622976);       // 4 MB
    unsigned short* Vt     = (unsigned short*)(ws + 14817280);       // 4 MB
    float*          partial= (float*)(ws + 19011584);                // 16 MB
    float*          mlb    = (float*)(ws + 35788800);                // 1 MB
    float*          lbuf   = (float*)(ws + 36837376);                // 256 KB
    unsigned short* attnO  = featb;                                  // alias (featb dead after k_qkv)

    k_feat<<<dim3(1024), dim3(256), 0, stream>>>(feat, featb);
    k_pack<<<dim3(4358), dim3(256), 0, stream>>>(qw, qb, kvw, kvb, pew, peb, pret, projw,
                                                 wqkv, bqkv, projwb, peAll);
    k_qkv<<<dim3(24, 32), dim3(256), 0, stream>>>(featb, wqkv, bqkv, Qh, Kh, Vt);
    k_attn<<<dim3(256), dim3(512), 0, stream>>>(Qh, Kh, Vt, pe_idx, peAll, blank_k,
                                                partial, mlb, lbuf);
    k_comb<<<dim3(8192), dim3(256), 0, stream>>>(partial, mlb, lbuf, blank_v, attnO);
    k_proj<<<dim3(8, 32), dim3(256), 0, stream>>>(attnO, projwb, projb, (float*)d_out);
}

// Round 3
// 104.547 us; speedup vs baseline: 1.5443x; 1.0130x over previous
//
#include <hip/hip_runtime.h>
#include <hip/hip_fp16.h>

typedef __attribute__((ext_vector_type(8))) short short8;
typedef __attribute__((ext_vector_type(8))) __bf16 bf16x8;
typedef __attribute__((ext_vector_type(4))) float f32x4;
typedef __attribute__((ext_vector_type(16))) float f32x16;

#define DEV __device__ __forceinline__

DEV unsigned short f2bf(float f) {
    unsigned int u = __float_as_uint(f);
    return (unsigned short)((u + 0x7FFFu + ((u >> 16) & 1u)) >> 16);
}
DEV float bf2f(unsigned short s) { return __uint_as_float(((unsigned int)s) << 16); }
DEV bf16x8 asbf(short8 v) { return __builtin_bit_cast(bf16x8, v); }

// ---------------- prep kernels ----------------

__global__ __launch_bounds__(256) void k_feat(const float* __restrict__ feat,
                                              unsigned short* __restrict__ featb) {
    int i = blockIdx.x * 256 + threadIdx.x;
    const float4* f4 = (const float4*)feat + (size_t)i * 2;
    float4 a = f4[0], c = f4[1];
    short8 o;
    o[0] = (short)f2bf(a.x); o[1] = (short)f2bf(a.y);
    o[2] = (short)f2bf(a.z); o[3] = (short)f2bf(a.w);
    o[4] = (short)f2bf(c.x); o[5] = (short)f2bf(c.y);
    o[6] = (short)f2bf(c.z); o[7] = (short)f2bf(c.w);
    ((short8*)featb)[i] = o;
}

__global__ __launch_bounds__(256) void k_pack(const float* __restrict__ qw, const float* __restrict__ qb,
                                              const float* __restrict__ kvw, const float* __restrict__ kvb,
                                              const float* __restrict__ pew, const float* __restrict__ peb,
                                              const float* __restrict__ pret, const float* __restrict__ projw,
                                              unsigned short* __restrict__ wqkv, float* __restrict__ bqkv,
                                              unsigned short* __restrict__ projwb, unsigned short* __restrict__ peAll) {
    const float scale = 0.17677669529663687f; // 1/sqrt(32)
    int i = blockIdx.x * 256 + threadIdx.x;
    if (i < 786432) {
        int o = i >> 9, k = i & 511;
        float v = (o < 512) ? qw[(o << 9) + k] * scale : kvw[((o - 512) << 9) + k];
        wqkv[i] = f2bf(v);
    } else if (i < 786432 + 262144) {
        int j = i - 786432;
        projwb[j] = f2bf(projw[j]);
    } else if (i < 786432 + 262144 + 1536) {
        int o = i - (786432 + 262144);
        bqkv[o] = (o < 512) ? qb[o] * scale : kvb[o - 512];
    } else if (i < 786432 + 262144 + 1536 + 65536) { // peAll[t][h] f16
        int j = i - (786432 + 262144 + 1536);
        int t = j >> 4, h = j & 15;
        float s = peb[h];
#pragma unroll
        for (int u = 0; u < 5; u++) s += pret[t * 5 + u] * pew[h * 5 + u];
        peAll[j] = __builtin_bit_cast(unsigned short, __float2half(s));
    }
}

// ---------------- QKV GEMM ----------------
__global__ __launch_bounds__(256) void k_qkv(const unsigned short* __restrict__ A,
                                             const unsigned short* __restrict__ Bw,
                                             const float* __restrict__ bias,
                                             unsigned short* __restrict__ Qh,
                                             unsigned short* __restrict__ Kh,
                                             unsigned short* __restrict__ Vt) {
    __shared__ __align__(16) unsigned short As[128][72];
    __shared__ __align__(16) unsigned short Bs[64][72];
    int tid = threadIdx.x, lane = tid & 63, wid = tid >> 6;
    int m0 = blockIdx.y * 128, n0 = blockIdx.x * 64;
    int wm = wid >> 1, wn = wid & 1;
    f32x4 acc[4][2] = {};

    for (int k0 = 0; k0 < 512; k0 += 64) {
        {
            int row = tid >> 1, cs = (tid & 1) * 32;
            const short8* src = (const short8*)(A + (size_t)(m0 + row) * 512 + k0 + cs);
            short8* dst = (short8*)(&As[row][cs]);
            dst[0] = src[0]; dst[1] = src[1]; dst[2] = src[2]; dst[3] = src[3];
        }
        {
            int row = tid >> 2, cs = (tid & 3) * 16;
            const short8* src = (const short8*)(Bw + (size_t)(n0 + row) * 512 + k0 + cs);
            short8* dst = (short8*)(&Bs[row][cs]);
            dst[0] = src[0]; dst[1] = src[1];
        }
        __syncthreads();
#pragma unroll
        for (int kk = 0; kk < 64; kk += 32) {
            short8 a[4], b[2];
#pragma unroll
            for (int m = 0; m < 4; m++)
                a[m] = *(const short8*)(&As[wm * 64 + m * 16 + (lane & 15)][kk + ((lane >> 4) << 3)]);
#pragma unroll
            for (int n = 0; n < 2; n++)
                b[n] = *(const short8*)(&Bs[wn * 32 + n * 16 + (lane & 15)][kk + ((lane >> 4) << 3)]);
#pragma unroll
            for (int m = 0; m < 4; m++) {
#pragma unroll
                for (int n = 0; n < 2; n++)
                    acc[m][n] = __builtin_amdgcn_mfma_f32_16x16x32_bf16(asbf(a[m]), asbf(b[n]), acc[m][n], 0, 0, 0);
            }
        }
        __syncthreads();
    }
#pragma unroll
    for (int m = 0; m < 4; m++) {
#pragma unroll
        for (int n = 0; n < 2; n++) {
            int col = n0 + wn * 32 + n * 16 + (lane & 15);
            float bv = bias[col];
#pragma unroll
            for (int r = 0; r < 4; r++) {
                int row = m0 + wm * 64 + m * 16 + ((lane >> 4) << 2) + r;
                float v = acc[m][n][r] + bv;
                unsigned short bb = f2bf(v);
                int batch = row >> 10, nn = row & 1023;
                if (col < 512) {
                    int h = col >> 5, d = col & 31;
                    Qh[((((batch << 4) + h) << 10) + nn) * 32 + d] = bb;
                } else {
                    int oo = col - 512, h = oo >> 6, rem = oo & 63;
                    if (rem < 32)
                        Kh[((((batch << 4) + h) << 10) + nn) * 32 + rem] = bb;
                    else
                        Vt[(((batch << 4) + h) * 32 + (rem - 32)) * 1024 + nn] = bb;
                }
            }
        }
    }
}

// ---------------- fused attention: 32x32 MFMA, permlane P-path, slab posb ----------------
// grid 256: b = bid&3, qt = (bid>>2)&31, kc = bid>>7; 512 threads = 8 waves;
// wave w owns heads 2w,2w+1; q-tile 32; k-chunk 512 in 8 tiles of 64.
__global__ __launch_bounds__(512, 2) void k_attn(const unsigned short* __restrict__ Qh,
                                                 const unsigned short* __restrict__ Kh,
                                                 const unsigned short* __restrict__ Vt,
                                                 const int* __restrict__ pe_idx,
                                                 const unsigned short* __restrict__ peAll,
                                                 const float* __restrict__ blank_k,
                                                 float* __restrict__ partial,
                                                 float* __restrict__ ml,
                                                 float* __restrict__ lbuf) {
    __shared__ __align__(16) unsigned int posb[8][32][72];   // 72 KB, pair-slabs, k padded 64->72

    int tid = threadIdx.x, lane = tid & 63, w = tid >> 6;
    int q5 = lane & 31, hi = lane >> 5;
    int bid = blockIdx.x;
    int b = bid & 3, rest = bid >> 2, qt = rest & 31, kc = rest >> 5;
    int q0 = qt * 32, k_base = kc * 512;

    // gather-phase map: thread -> (q row, 4 consecutive k)
    int gq = tid >> 4, gk = (tid & 15) * 4;
    const int* pebase = pe_idx + ((size_t)((b << 10) + q0 + gq)) * 1024 + k_base + gk;

    short8 qf[2][2];
    float lb_[2], m_run[2], l_run[2];
    f32x16 accO[2] = {};
    const f32x16 zero16 = {};

#pragma unroll
    for (int hh = 0; hh < 2; hh++) {
        int head = 2 * w + hh, bh = (b << 4) + head;
#pragma unroll
        for (int sub = 0; sub < 2; sub++)
            qf[hh][sub] = *(const short8*)(Qh + ((size_t)((bh << 10) + q0 + q5)) * 32 + sub * 16 + hi * 8);
        float dot = 0.f;
#pragma unroll
        for (int sub = 0; sub < 2; sub++) {
            const float* bk = blank_k + head * 32 + sub * 16 + hi * 8;
#pragma unroll
            for (int t = 0; t < 8; t++) dot += bf2f((unsigned short)qf[hh][sub][t]) * bk[t];
        }
        dot += __shfl_xor(dot, 32, 64);
        lb_[hh] = dot;
        m_run[hh] = (kc == 0) ? dot : -1e30f;
        l_run[hh] = (kc == 0) ? 1.0f : 0.0f;
    }

    // prologue gather (tile 0) into regs: gg[slab dword][el]
    unsigned gg[8][4];
    {
        int4 idx = *(const int4*)(pebase);
        int id[4] = {idx.x, idx.y, idx.z, idx.w};
#pragma unroll
        for (int j = 0; j < 4; j++) {
            uint4 a = *(const uint4*)(peAll + ((size_t)id[j] << 4));
            uint4 c = *(const uint4*)(peAll + ((size_t)id[j] << 4) + 8);
            gg[0][j] = a.x; gg[1][j] = a.y; gg[2][j] = a.z; gg[3][j] = a.w;
            gg[4][j] = c.x; gg[5][j] = c.y; gg[6][j] = c.z; gg[7][j] = c.w;
        }
    }

    for (int kt = 0; kt < 8; kt++) {
        __syncthreads();                       // previous tile fully consumed
#pragma unroll
        for (int p = 0; p < 8; p++) {          // b128 writes, bank-floor
            uint4 o = {gg[p][0], gg[p][1], gg[p][2], gg[p][3]};
            *(uint4*)&posb[p][gq][gk] = o;
        }
        if (kt < 7) {                          // prefetch next tile's gathers into regs
            int4 idx = *(const int4*)(pebase + (kt + 1) * 64);
            int id[4] = {idx.x, idx.y, idx.z, idx.w};
#pragma unroll
            for (int j = 0; j < 4; j++) {
                uint4 a = *(const uint4*)(peAll + ((size_t)id[j] << 4));
                uint4 c = *(const uint4*)(peAll + ((size_t)id[j] << 4) + 8);
                gg[0][j] = a.x; gg[1][j] = a.y; gg[2][j] = a.z; gg[3][j] = a.w;
                gg[4][j] = c.x; gg[5][j] = c.y; gg[6][j] = c.z; gg[7][j] = c.w;
            }
        }
        __syncthreads();                       // posb[kt] ready

        // pos dwords for this wave's head pair: b128 reads, bank-floor
        unsigned pu[2][4][4];
#pragma unroll
        for (int ks = 0; ks < 2; ks++)
#pragma unroll
            for (int rr = 0; rr < 4; rr++) {
                uint4 v = *(const uint4*)&posb[w][q5][ks * 32 + rr * 8 + hi * 4];
                pu[ks][rr][0] = v.x; pu[ks][rr][1] = v.y; pu[ks][rr][2] = v.z; pu[ks][rr][3] = v.w;
            }

        int kg0 = k_base + kt * 64;
#pragma unroll
        for (int hh = 0; hh < 2; hh++) {
            int bh = (b << 4) + 2 * w + hh;
            // S^T = K x Q^T (32k x 32q), rows k=(r&3)+8*(r>>2)+4*hi, col q=q5
            f32x16 st[2];
#pragma unroll
            for (int ks = 0; ks < 2; ks++) {
                const unsigned short* kp = Kh + ((size_t)((bh << 10) + kg0 + ks * 32 + q5)) * 32 + hi * 8;
                short8 kf0 = *(const short8*)(kp);
                short8 kf1 = *(const short8*)(kp + 16);
                st[ks] = __builtin_amdgcn_mfma_f32_32x32x16_bf16(asbf(kf0), asbf(qf[hh][0]), zero16, 0, 0, 0);
                st[ks] = __builtin_amdgcn_mfma_f32_32x32x16_bf16(asbf(kf1), asbf(qf[hh][1]), st[ks], 0, 0, 0);
            }
            // pos add + tile max
            float mx = -1e30f;
#pragma unroll
            for (int ks = 0; ks < 2; ks++)
#pragma unroll
                for (int r = 0; r < 16; r++) {
                    __half2 h2 = __builtin_bit_cast(__half2, pu[ks][r >> 2][r & 3]);
                    st[ks][r] += hh ? __high2float(h2) : __low2float(h2);
                    mx = fmaxf(mx, st[ks][r]);
                }
            mx = fmaxf(mx, __shfl_xor(mx, 32, 64));
            // defer-max (T13): only rescale when growth > 8
            if (!__all(mx <= m_run[hh] + 8.0f)) {
                float mn = fmaxf(m_run[hh], mx);
                float fac = __expf(m_run[hh] - mn);
                m_run[hh] = mn;
                l_run[hh] *= fac;
#pragma unroll
                for (int r = 0; r < 16; r++) {
                    int qrow = (r & 3) + 8 * (r >> 2) + 4 * hi;
                    float facr = __shfl(fac, qrow, 64);
                    accO[hh][r] *= facr;
                }
            }
            float sum = 0.f;
#pragma unroll
            for (int ks = 0; ks < 2; ks++)
#pragma unroll
                for (int r = 0; r < 16; r++) {
                    float p = __expf(st[ks][r] - m_run[hh]);
                    st[ks][r] = p;
                    sum += p;
                }
            sum += __shfl_xor(sum, 32, 64);
            l_run[hh] += sum;
            // P -> A-frag via pack + permlane32_swap (T12), then PV
#pragma unroll
            for (int ks = 0; ks < 2; ks++) {
                unsigned pk_[8];
#pragma unroll
                for (int i = 0; i < 8; i++)
                    pk_[i] = (unsigned)f2bf(st[ks][2 * i]) | ((unsigned)f2bf(st[ks][2 * i + 1]) << 16);
                asm("v_permlane32_swap_b32 %0, %1" : "+v"(pk_[0]), "+v"(pk_[2]));
                asm("v_permlane32_swap_b32 %0, %1" : "+v"(pk_[1]), "+v"(pk_[3]));
                asm("v_permlane32_swap_b32 %0, %1" : "+v"(pk_[4]), "+v"(pk_[6]));
                asm("v_permlane32_swap_b32 %0, %1" : "+v"(pk_[5]), "+v"(pk_[7]));
                uint4 u0 = {pk_[0], pk_[1], pk_[2], pk_[3]};
                uint4 u1 = {pk_[4], pk_[5], pk_[6], pk_[7]};
                short8 pa0 = __builtin_bit_cast(short8, u0);
                short8 pa1 = __builtin_bit_cast(short8, u1);
                const unsigned short* vp = Vt + ((size_t)(bh * 32 + q5)) * 1024 + kg0 + ks * 32 + hi * 8;
                short8 vf0 = *(const short8*)(vp);
                short8 vf1 = *(const short8*)(vp + 16);
                accO[hh] = __builtin_amdgcn_mfma_f32_32x32x16_bf16(asbf(pa0), asbf(vf0), accO[hh], 0, 0, 0);
                accO[hh] = __builtin_amdgcn_mfma_f32_32x32x16_bf16(asbf(pa1), asbf(vf1), accO[hh], 0, 0, 0);
            }
        }
    }

    // epilogue: write partials (O rows q, cols d=q5)
#pragma unroll
    for (int hh = 0; hh < 2; hh++) {
        int head = 2 * w + hh;
        size_t base = ((size_t)((b * 2 + kc) * 16 + head)) << 10;
#pragma unroll
        for (int r = 0; r < 16; r++) {
            int qrow = (r & 3) + 8 * (r >> 2) + 4 * hi;
            partial[(base + q0 + qrow) * 32 + q5] = accO[hh][r];
        }
        if (hi == 0) {
            ml[(base + q0 + q5) * 2 + 0] = m_run[hh];
            ml[(base + q0 + q5) * 2 + 1] = l_run[hh];
            if (kc == 0)
                lbuf[(((size_t)((b << 4) + head)) << 10) + q0 + q5] = lb_[hh];
        }
    }
}

// ---------------- combine partials + blank ----------------
__global__ __launch_bounds__(256) void k_comb(const float* __restrict__ partial,
                                              const float* __restrict__ ml,
                                              const float* __restrict__ lbuf,
                                              const float* __restrict__ blank_v,
                                              unsigned short* __restrict__ attnO) {
    int t = blockIdx.x * 256 + threadIdx.x;
    int d = t & 31;
    int row = t >> 5;
    int b = row >> 14, h = (row >> 10) & 15, q = row & 1023;
    size_t iA = ((size_t)((b * 2 + 0) * 16 + h) << 10) + q;
    size_t iB = ((size_t)((b * 2 + 1) * 16 + h) << 10) + q;
    float mA = ml[iA * 2], lA = ml[iA * 2 + 1];
    float mB = ml[iB * 2], lB = ml[iB * 2 + 1];
    float lb = lbuf[row];
    float M = fmaxf(mA, mB);
    float eA = __expf(mA - M), eB = __expf(mB - M);
    float L = lA * eA + lB * eB;
    float val = (partial[iA * 32 + d] * eA + partial[iB * 32 + d] * eB) / L
              + __expf(lb - M) / L * blank_v[h * 32 + d];
    attnO[((size_t)((b << 10) + q)) * 512 + h * 32 + d] = f2bf(val);
}

// ---------------- final projection GEMM ----------------
__global__ __launch_bounds__(256) void k_proj(const unsigned short* __restrict__ A,
                                              const unsigned short* __restrict__ Bw,
                                              const float* __restrict__ bias,
                                              float* __restrict__ out) {
    __shared__ __align__(16) unsigned short As[128][72];
    __shared__ __align__(16) unsigned short Bs[64][72];
    int tid = threadIdx.x, lane = tid & 63, wid = tid >> 6;
    int m0 = blockIdx.y * 128, n0 = blockIdx.x * 64;
    int wm = wid >> 1, wn = wid & 1;
    f32x4 acc[4][2] = {};

    for (int k0 = 0; k0 < 512; k0 += 64) {
        {
            int row = tid >> 1, cs = (tid & 1) * 32;
            const short8* src = (const short8*)(A + (size_t)(m0 + row) * 512 + k0 + cs);
            short8* dst = (short8*)(&As[row][cs]);
            dst[0] = src[0]; dst[1] = src[1]; dst[2] = src[2]; dst[3] = src[3];
        }
        {
            int row = tid >> 2, cs = (tid & 3) * 16;
            const short8* src = (const short8*)(Bw + (size_t)(n0 + row) * 512 + k0 + cs);
            short8* dst = (short8*)(&Bs[row][cs]);
            dst[0] = src[0]; dst[1] = src[1];
        }
        __syncthreads();
#pragma unroll
        for (int kk = 0; kk < 64; kk += 32) {
            short8 a[4], b[2];
#pragma unroll
            for (int m = 0; m < 4; m++)
                a[m] = *(const short8*)(&As[wm * 64 + m * 16 + (lane & 15)][kk + ((lane >> 4) << 3)]);
#pragma unroll
            for (int n = 0; n < 2; n++)
                b[n] = *(const short8*)(&Bs[wn * 32 + n * 16 + (lane & 15)][kk + ((lane >> 4) << 3)]);
#pragma unroll
            for (int m = 0; m < 4; m++) {
#pragma unroll
                for (int n = 0; n < 2; n++)
                    acc[m][n] = __builtin_amdgcn_mfma_f32_16x16x32_bf16(asbf(a[m]), asbf(b[n]), acc[m][n], 0, 0, 0);
            }
        }
        __syncthreads();
    }
#pragma unroll
    for (int m = 0; m < 4; m++) {
#pragma unroll
        for (int n = 0; n < 2; n++) {
            int col = n0 + wn * 32 + n * 16 + (lane & 15);
            float bv = bias[col];
#pragma unroll
            for (int r = 0; r < 4; r++) {
                int row = m0 + wm * 64 + m * 16 + ((lane >> 4) << 2) + r;
                out[(size_t)row * 512 + col] = acc[m][n][r] + bv;
            }
        }
    }
}

extern "C" void kernel_launch(void* const* d_in, const int* in_sizes, int n_in,
                              void* d_out, int out_size, void* d_ws, size_t ws_size,
                              hipStream_t stream) {
    const float* feat    = (const float*)d_in[0];
    const int*   pe_idx  = (const int*)d_in[3];
    const float* pret    = (const float*)d_in[5];
    const float* qw      = (const float*)d_in[6];
    const float* qb      = (const float*)d_in[7];
    const float* kvw     = (const float*)d_in[8];
    const float* kvb     = (const float*)d_in[9];
    const float* pew     = (const float*)d_in[10];
    const float* peb     = (const float*)d_in[11];
    const float* blank_k = (const float*)d_in[12];
    const float* blank_v = (const float*)d_in[13];
    const float* projw   = (const float*)d_in[14];
    const float* projb   = (const float*)d_in[15];

    char* ws = (char*)d_ws;
    unsigned short* featb  = (unsigned short*)(ws);                  // 4 MB (reused as attnO)
    unsigned short* wqkv   = (unsigned short*)(ws + 4194304);        // 1.5 MB
    unsigned short* projwb = (unsigned short*)(ws + 5767168);        // 0.5 MB
    float*          bqkv   = (float*)(ws + 6291456);                 // 6 KB
    unsigned short* peAll  = (unsigned short*)(ws + 6297600);        // 128 KB
    unsigned short* Qh     = (unsigned short*)(ws + 6428672);        // 4 MB
    unsigned short* Kh     = (unsigned short*)(ws + 10622976);       // 4 MB
    unsigned short* Vt     = (unsigned short*)(ws + 14817280);       // 4 MB
    float*          partial= (float*)(ws + 19011584);                // 16 MB
    float*          mlb    = (float*)(ws + 35788800);                // 1 MB
    float*          lbuf   = (float*)(ws + 36837376);                // 256 KB
    unsigned short* attnO  = featb;                                  // alias (featb dead after k_qkv)

    k_feat<<<dim3(1024), dim3(256), 0, stream>>>(feat, featb);
    k_pack<<<dim3(4358), dim3(256), 0, stream>>>(qw, qb, kvw, kvb, pew, peb, pret, projw,
                                                 wqkv, bqkv, projwb, peAll);
    k_qkv<<<dim3(24, 32), dim3(256), 0, stream>>>(featb, wqkv, bqkv, Qh, Kh, Vt);
    k_attn<<<dim3(256), dim3(512), 0, stream>>>(Qh, Kh, Vt, pe_idx, peAll, blank_k,
                                                partial, mlb, lbuf);
    k_comb<<<dim3(8192), dim3(256), 0, stream>>>(partial, mlb, lbuf, blank_v, attnO);
    k_proj<<<dim3(8, 32), dim3(256), 0, stream>>>(attnO, projwb, projb, (float*)d_out);
}

// Round 4
// 101.012 us; speedup vs baseline: 1.5984x; 1.0350x over previous
//
#include <hip/hip_runtime.h>
#include <hip/hip_fp16.h>

typedef __attribute__((ext_vector_type(8))) short short8;
typedef __attribute__((ext_vector_type(8))) __bf16 bf16x8;
typedef __attribute__((ext_vector_type(4))) float f32x4;
typedef __attribute__((ext_vector_type(16))) float f32x16;

#define DEV __device__ __forceinline__

DEV unsigned short f2bf(float f) {
    unsigned int u = __float_as_uint(f);
    return (unsigned short)((u + 0x7FFFu + ((u >> 16) & 1u)) >> 16);
}
DEV float bf2f(unsigned short s) { return __uint_as_float(((unsigned int)s) << 16); }
DEV bf16x8 asbf(short8 v) { return __builtin_bit_cast(bf16x8, v); }

// ---------------- prep kernel (feat cast + weight pack fused) ----------------
__global__ __launch_bounds__(256) void k_prep(const float* __restrict__ feat,
                                              const float* __restrict__ qw, const float* __restrict__ qb,
                                              const float* __restrict__ kvw, const float* __restrict__ kvb,
                                              const float* __restrict__ pew, const float* __restrict__ peb,
                                              const float* __restrict__ pret, const float* __restrict__ projw,
                                              unsigned short* __restrict__ featb,
                                              unsigned short* __restrict__ wqkv, float* __restrict__ bqkv,
                                              unsigned short* __restrict__ projwb, unsigned short* __restrict__ peAll) {
    const float scale = 0.17677669529663687f; // 1/sqrt(32)
    int i0 = blockIdx.x * 256 + threadIdx.x;
    if (i0 < 262144) {                        // feat f32 -> bf16, 8/thread
        const float4* f4 = (const float4*)feat + (size_t)i0 * 2;
        float4 a = f4[0], c = f4[1];
        short8 o;
        o[0] = (short)f2bf(a.x); o[1] = (short)f2bf(a.y);
        o[2] = (short)f2bf(a.z); o[3] = (short)f2bf(a.w);
        o[4] = (short)f2bf(c.x); o[5] = (short)f2bf(c.y);
        o[6] = (short)f2bf(c.z); o[7] = (short)f2bf(c.w);
        ((short8*)featb)[i0] = o;
        return;
    }
    int i = i0 - 262144;
    if (i < 786432) {                         // wqkv [1536][512]
        int o = i >> 9, k = i & 511;
        float v = (o < 512) ? qw[(o << 9) + k] * scale : kvw[((o - 512) << 9) + k];
        wqkv[i] = f2bf(v);
    } else if (i < 786432 + 262144) {
        int j = i - 786432;
        projwb[j] = f2bf(projw[j]);
    } else if (i < 786432 + 262144 + 1536) {
        int o = i - (786432 + 262144);
        bqkv[o] = (o < 512) ? qb[o] * scale : kvb[o - 512];
    } else if (i < 786432 + 262144 + 1536 + 65536) { // peAll[t][16] f16
        int j = i - (786432 + 262144 + 1536);
        int t = j >> 4, h = j & 15;
        float s = peb[h];
#pragma unroll
        for (int u = 0; u < 5; u++) s += pret[t * 5 + u] * pew[h * 5 + u];
        peAll[j] = __builtin_bit_cast(unsigned short, __float2half(s));
    }
}

// ---------------- QKV GEMM ----------------
__global__ __launch_bounds__(256) void k_qkv(const unsigned short* __restrict__ A,
                                             const unsigned short* __restrict__ Bw,
                                             const float* __restrict__ bias,
                                             unsigned short* __restrict__ Qh,
                                             unsigned short* __restrict__ Kh,
                                             unsigned short* __restrict__ Vt) {
    __shared__ __align__(16) unsigned short As[128][72];
    __shared__ __align__(16) unsigned short Bs[64][72];
    int tid = threadIdx.x, lane = tid & 63, wid = tid >> 6;
    int m0 = blockIdx.y * 128, n0 = blockIdx.x * 64;
    int wm = wid >> 1, wn = wid & 1;
    f32x4 acc[4][2] = {};

    for (int k0 = 0; k0 < 512; k0 += 64) {
        {
            int row = tid >> 1, cs = (tid & 1) * 32;
            const short8* src = (const short8*)(A + (size_t)(m0 + row) * 512 + k0 + cs);
            short8* dst = (short8*)(&As[row][cs]);
            dst[0] = src[0]; dst[1] = src[1]; dst[2] = src[2]; dst[3] = src[3];
        }
        {
            int row = tid >> 2, cs = (tid & 3) * 16;
            const short8* src = (const short8*)(Bw + (size_t)(n0 + row) * 512 + k0 + cs);
            short8* dst = (short8*)(&Bs[row][cs]);
            dst[0] = src[0]; dst[1] = src[1];
        }
        __syncthreads();
#pragma unroll
        for (int kk = 0; kk < 64; kk += 32) {
            short8 a[4], b[2];
#pragma unroll
            for (int m = 0; m < 4; m++)
                a[m] = *(const short8*)(&As[wm * 64 + m * 16 + (lane & 15)][kk + ((lane >> 4) << 3)]);
#pragma unroll
            for (int n = 0; n < 2; n++)
                b[n] = *(const short8*)(&Bs[wn * 32 + n * 16 + (lane & 15)][kk + ((lane >> 4) << 3)]);
#pragma unroll
            for (int m = 0; m < 4; m++) {
#pragma unroll
                for (int n = 0; n < 2; n++)
                    acc[m][n] = __builtin_amdgcn_mfma_f32_16x16x32_bf16(asbf(a[m]), asbf(b[n]), acc[m][n], 0, 0, 0);
            }
        }
        __syncthreads();
    }
#pragma unroll
    for (int m = 0; m < 4; m++) {
#pragma unroll
        for (int n = 0; n < 2; n++) {
            int col = n0 + wn * 32 + n * 16 + (lane & 15);
            float bv = bias[col];
#pragma unroll
            for (int r = 0; r < 4; r++) {
                int row = m0 + wm * 64 + m * 16 + ((lane >> 4) << 2) + r;
                float v = acc[m][n][r] + bv;
                unsigned short bb = f2bf(v);
                int batch = row >> 10, nn = row & 1023;
                if (col < 512) {
                    int h = col >> 5, d = col & 31;
                    Qh[((((batch << 4) + h) << 10) + nn) * 32 + d] = bb;
                } else {
                    int oo = col - 512, h = oo >> 6, rem = oo & 63;
                    if (rem < 32)
                        Kh[((((batch << 4) + h) << 10) + nn) * 32 + rem] = bb;
                    else
                        Vt[(((batch << 4) + h) * 32 + (rem - 32)) * 1024 + nn] = bb;
                }
            }
        }
    }
}

// ---------------- fused attention: 8 heads/block, 1 head/wave, kc split ----------------
// grid 512: b=bid&3, qt=(bid>>2)&31, kc=(bid>>7)&1, hg=bid>>8
// 512 threads = 8 waves; wave w -> head hg*8+w; q-tile 32; k-chunk 512 in 8 tiles of 64
__global__ __launch_bounds__(512, 4) void k_attn(const unsigned short* __restrict__ Qh,
                                                 const unsigned short* __restrict__ Kh,
                                                 const unsigned short* __restrict__ Vt,
                                                 const int* __restrict__ pe_idx,
                                                 const unsigned short* __restrict__ peAll,
                                                 const float* __restrict__ blank_k,
                                                 float* __restrict__ partial,
                                                 float* __restrict__ ml,
                                                 float* __restrict__ lbuf) {
    __shared__ __align__(16) unsigned int posb[4][32][72];   // 36 KB: 4 dword-slabs (2 heads each)

    int tid = threadIdx.x, lane = tid & 63, w = tid >> 6;
    int q5 = lane & 31, hi = lane >> 5;
    int bid = blockIdx.x;
    int b = bid & 3, qt = (bid >> 2) & 31, kc = (bid >> 7) & 1, hg = bid >> 8;
    int q0 = qt * 32, k_base = kc * 512;
    int head = hg * 8 + w, bh = (b << 4) + head;
    int slab = w >> 1, halfsel = w & 1;

    // gather-phase map: thread -> (q row, 4 consecutive k)
    int gq = tid >> 4, gk = (tid & 15) * 4;
    const int* pebase = pe_idx + ((size_t)((b << 10) + q0 + gq)) * 1024 + k_base + gk;
    const unsigned short* peg = peAll + hg * 8;   // this head-group's 16B half-row

    short8 qf[2];
    float lb_, m_run, l_run;
    f32x16 accO = {};
    const f32x16 zero16 = {};

    {
#pragma unroll
        for (int sub = 0; sub < 2; sub++)
            qf[sub] = *(const short8*)(Qh + ((size_t)((bh << 10) + q0 + q5)) * 32 + sub * 16 + hi * 8);
        float dot = 0.f;
#pragma unroll
        for (int sub = 0; sub < 2; sub++) {
            const float* bk = blank_k + head * 32 + sub * 16 + hi * 8;
#pragma unroll
            for (int t = 0; t < 8; t++) dot += bf2f((unsigned short)qf[sub][t]) * bk[t];
        }
        dot += __shfl_xor(dot, 32, 64);
        lb_ = dot;
        m_run = (kc == 0) ? dot : -1e30f;
        l_run = (kc == 0) ? 1.0f : 0.0f;
    }

    // prologue gather (tile 0): gg[slab dword][j]
    unsigned gg[4][4];
    {
        int4 idx = *(const int4*)(pebase);
        int id[4] = {idx.x, idx.y, idx.z, idx.w};
#pragma unroll
        for (int j = 0; j < 4; j++) {
            uint4 a = *(const uint4*)(peg + ((size_t)id[j] << 4));
            gg[0][j] = a.x; gg[1][j] = a.y; gg[2][j] = a.z; gg[3][j] = a.w;
        }
    }

    for (int kt = 0; kt < 8; kt++) {
        __syncthreads();                       // previous tile fully consumed
#pragma unroll
        for (int p = 0; p < 4; p++) {          // b128 writes, bank-floor
            uint4 o = {gg[p][0], gg[p][1], gg[p][2], gg[p][3]};
            *(uint4*)&posb[p][gq][gk] = o;
        }
        if (kt < 7) {                          // prefetch next tile's gathers into regs
            int4 idx = *(const int4*)(pebase + (kt + 1) * 64);
            int id[4] = {idx.x, idx.y, idx.z, idx.w};
#pragma unroll
            for (int j = 0; j < 4; j++) {
                uint4 a = *(const uint4*)(peg + ((size_t)id[j] << 4));
                gg[0][j] = a.x; gg[1][j] = a.y; gg[2][j] = a.z; gg[3][j] = a.w;
            }
        }
        __syncthreads();                       // posb[kt] ready

        // pos dwords for this wave's head: b128 reads, bank-floor
        unsigned pu[2][4][4];
#pragma unroll
        for (int ks = 0; ks < 2; ks++)
#pragma unroll
            for (int rr = 0; rr < 4; rr++) {
                uint4 v = *(const uint4*)&posb[slab][q5][ks * 32 + rr * 8 + hi * 4];
                pu[ks][rr][0] = v.x; pu[ks][rr][1] = v.y; pu[ks][rr][2] = v.z; pu[ks][rr][3] = v.w;
            }

        int kg0 = k_base + kt * 64;
        // S^T = K x Q^T (32k x 32q), rows k=(r&3)+8*(r>>2)+4*hi, col q=q5
        f32x16 st[2];
#pragma unroll
        for (int ks = 0; ks < 2; ks++) {
            const unsigned short* kp = Kh + ((size_t)((bh << 10) + kg0 + ks * 32 + q5)) * 32 + hi * 8;
            short8 kf0 = *(const short8*)(kp);
            short8 kf1 = *(const short8*)(kp + 16);
            st[ks] = __builtin_amdgcn_mfma_f32_32x32x16_bf16(asbf(kf0), asbf(qf[0]), zero16, 0, 0, 0);
            st[ks] = __builtin_amdgcn_mfma_f32_32x32x16_bf16(asbf(kf1), asbf(qf[1]), st[ks], 0, 0, 0);
        }
        // pos add + tile max
        float mx = -1e30f;
#pragma unroll
        for (int ks = 0; ks < 2; ks++)
#pragma unroll
            for (int r = 0; r < 16; r++) {
                __half2 h2 = __builtin_bit_cast(__half2, pu[ks][r >> 2][r & 3]);
                st[ks][r] += halfsel ? __high2float(h2) : __low2float(h2);
                mx = fmaxf(mx, st[ks][r]);
            }
        mx = fmaxf(mx, __shfl_xor(mx, 32, 64));
        // defer-max (T13)
        if (!__all(mx <= m_run + 8.0f)) {
            float mn = fmaxf(m_run, mx);
            float fac = __expf(m_run - mn);
            m_run = mn;
            l_run *= fac;
#pragma unroll
            for (int r = 0; r < 16; r++) {
                int qrow = (r & 3) + 8 * (r >> 2) + 4 * hi;
                float facr = __shfl(fac, qrow, 64);
                accO[r] *= facr;
            }
        }
        float sum = 0.f;
#pragma unroll
        for (int ks = 0; ks < 2; ks++)
#pragma unroll
            for (int r = 0; r < 16; r++) {
                float p = __expf(st[ks][r] - m_run);
                st[ks][r] = p;
                sum += p;
            }
        sum += __shfl_xor(sum, 32, 64);
        l_run += sum;
        // P -> A-frag via v_cvt_pk_bf16_f32 + permlane32_swap (T12), then PV
#pragma unroll
        for (int ks = 0; ks < 2; ks++) {
            unsigned pk_[8];
#pragma unroll
            for (int i = 0; i < 8; i++) {
                float plo = st[ks][2 * i], phi = st[ks][2 * i + 1];
                asm("v_cvt_pk_bf16_f32 %0, %1, %2" : "=v"(pk_[i]) : "v"(plo), "v"(phi));
            }
            asm("v_permlane32_swap_b32 %0, %1" : "+v"(pk_[0]), "+v"(pk_[2]));
            asm("v_permlane32_swap_b32 %0, %1" : "+v"(pk_[1]), "+v"(pk_[3]));
            asm("v_permlane32_swap_b32 %0, %1" : "+v"(pk_[4]), "+v"(pk_[6]));
            asm("v_permlane32_swap_b32 %0, %1" : "+v"(pk_[5]), "+v"(pk_[7]));
            uint4 u0 = {pk_[0], pk_[1], pk_[2], pk_[3]};
            uint4 u1 = {pk_[4], pk_[5], pk_[6], pk_[7]};
            short8 pa0 = __builtin_bit_cast(short8, u0);
            short8 pa1 = __builtin_bit_cast(short8, u1);
            const unsigned short* vp = Vt + ((size_t)(bh * 32 + q5)) * 1024 + kg0 + ks * 32 + hi * 8;
            short8 vf0 = *(const short8*)(vp);
            short8 vf1 = *(const short8*)(vp + 16);
            accO = __builtin_amdgcn_mfma_f32_32x32x16_bf16(asbf(pa0), asbf(vf0), accO, 0, 0, 0);
            accO = __builtin_amdgcn_mfma_f32_32x32x16_bf16(asbf(pa1), asbf(vf1), accO, 0, 0, 0);
        }
    }

    // epilogue
    {
        size_t base = ((size_t)((b * 2 + kc) * 16 + head)) << 10;
#pragma unroll
        for (int r = 0; r < 16; r++) {
            int qrow = (r & 3) + 8 * (r >> 2) + 4 * hi;
            partial[(base + q0 + qrow) * 32 + q5] = accO[r];
        }
        if (hi == 0) {
            ml[(base + q0 + q5) * 2 + 0] = m_run;
            ml[(base + q0 + q5) * 2 + 1] = l_run;
            if (kc == 0)
                lbuf[(((size_t)((b << 4) + head)) << 10) + q0 + q5] = lb_;
        }
    }
}

// ---------------- combine partials + blank ----------------
__global__ __launch_bounds__(256) void k_comb(const float* __restrict__ partial,
                                              const float* __restrict__ ml,
                                              const float* __restrict__ lbuf,
                                              const float* __restrict__ blank_v,
                                              unsigned short* __restrict__ attnO) {
    int t = blockIdx.x * 256 + threadIdx.x;
    int d = t & 31;
    int row = t >> 5;
    int b = row >> 14, h = (row >> 10) & 15, q = row & 1023;
    size_t iA = ((size_t)((b * 2 + 0) * 16 + h) << 10) + q;
    size_t iB = ((size_t)((b * 2 + 1) * 16 + h) << 10) + q;
    float mA = ml[iA * 2], lA = ml[iA * 2 + 1];
    float mB = ml[iB * 2], lB = ml[iB * 2 + 1];
    float lb = lbuf[row];
    float M = fmaxf(mA, mB);
    float eA = __expf(mA - M), eB = __expf(mB - M);
    float L = lA * eA + lB * eB;
    float val = (partial[iA * 32 + d] * eA + partial[iB * 32 + d] * eB) / L
              + __expf(lb - M) / L * blank_v[h * 32 + d];
    attnO[((size_t)((b << 10) + q)) * 512 + h * 32 + d] = f2bf(val);
}

// ---------------- final projection GEMM ----------------
__global__ __launch_bounds__(256) void k_proj(const unsigned short* __restrict__ A,
                                              const unsigned short* __restrict__ Bw,
                                              const float* __restrict__ bias,
                                              float* __restrict__ out) {
    __shared__ __align__(16) unsigned short As[128][72];
    __shared__ __align__(16) unsigned short Bs[64][72];
    int tid = threadIdx.x, lane = tid & 63, wid = tid >> 6;
    int m0 = blockIdx.y * 128, n0 = blockIdx.x * 64;
    int wm = wid >> 1, wn = wid & 1;
    f32x4 acc[4][2] = {};

    for (int k0 = 0; k0 < 512; k0 += 64) {
        {
            int row = tid >> 1, cs = (tid & 1) * 32;
            const short8* src = (const short8*)(A + (size_t)(m0 + row) * 512 + k0 + cs);
            short8* dst = (short8*)(&As[row][cs]);
            dst[0] = src[0]; dst[1] = src[1]; dst[2] = src[2]; dst[3] = src[3];
        }
        {
            int row = tid >> 2, cs = (tid & 3) * 16;
            const short8* src = (const short8*)(Bw + (size_t)(n0 + row) * 512 + k0 + cs);
            short8* dst = (short8*)(&Bs[row][cs]);
            dst[0] = src[0]; dst[1] = src[1];
        }
        __syncthreads();
#pragma unroll
        for (int kk = 0; kk < 64; kk += 32) {
            short8 a[4], b[2];
#pragma unroll
            for (int m = 0; m < 4; m++)
                a[m] = *(const short8*)(&As[wm * 64 + m * 16 + (lane & 15)][kk + ((lane >> 4) << 3)]);
#pragma unroll
            for (int n = 0; n < 2; n++)
                b[n] = *(const short8*)(&Bs[wn * 32 + n * 16 + (lane & 15)][kk + ((lane >> 4) << 3)]);
#pragma unroll
            for (int m = 0; m < 4; m++) {
#pragma unroll
                for (int n = 0; n < 2; n++)
                    acc[m][n] = __builtin_amdgcn_mfma_f32_16x16x32_bf16(asbf(a[m]), asbf(b[n]), acc[m][n], 0, 0, 0);
            }
        }
        __syncthreads();
    }
#pragma unroll
    for (int m = 0; m < 4; m++) {
#pragma unroll
        for (int n = 0; n < 2; n++) {
            int col = n0 + wn * 32 + n * 16 + (lane & 15);
            float bv = bias[col];
#pragma unroll
            for (int r = 0; r < 4; r++) {
                int row = m0 + wm * 64 + m * 16 + ((lane >> 4) << 2) + r;
                out[(size_t)row * 512 + col] = acc[m][n][r] + bv;
            }
        }
    }
}

extern "C" void kernel_launch(void* const* d_in, const int* in_sizes, int n_in,
                              void* d_out, int out_size, void* d_ws, size_t ws_size,
                              hipStream_t stream) {
    const float* feat    = (const float*)d_in[0];
    const int*   pe_idx  = (const int*)d_in[3];
    const float* pret    = (const float*)d_in[5];
    const float* qw      = (const float*)d_in[6];
    const float* qb      = (const float*)d_in[7];
    const float* kvw     = (const float*)d_in[8];
    const float* kvb     = (const float*)d_in[9];
    const float* pew     = (const float*)d_in[10];
    const float* peb     = (const float*)d_in[11];
    const float* blank_k = (const float*)d_in[12];
    const float* blank_v = (const float*)d_in[13];
    const float* projw   = (const float*)d_in[14];
    const float* projb   = (const float*)d_in[15];

    char* ws = (char*)d_ws;
    unsigned short* featb  = (unsigned short*)(ws);                  // 4 MB (reused as attnO)
    unsigned short* wqkv   = (unsigned short*)(ws + 4194304);        // 1.5 MB
    unsigned short* projwb = (unsigned short*)(ws + 5767168);        // 0.5 MB
    float*          bqkv   = (float*)(ws + 6291456);                 // 6 KB
    unsigned short* peAll  = (unsigned short*)(ws + 6297600);        // 128 KB
    unsigned short* Qh     = (unsigned short*)(ws + 6428672);        // 4 MB
    unsigned short* Kh     = (unsigned short*)(ws + 10622976);       // 4 MB
    unsigned short* Vt     = (unsigned short*)(ws + 14817280);       // 4 MB
    float*          partial= (float*)(ws + 19011584);                // 16 MB
    float*          mlb    = (float*)(ws + 35788800);                // 1 MB
    float*          lbuf   = (float*)(ws + 36837376);                // 256 KB
    unsigned short* attnO  = featb;                                  // alias (featb dead after k_qkv)

    k_prep<<<dim3(5382), dim3(256), 0, stream>>>(feat, qw, qb, kvw, kvb, pew, peb, pret, projw,
                                                 featb, wqkv, bqkv, projwb, peAll);
    k_qkv<<<dim3(24, 32), dim3(256), 0, stream>>>(featb, wqkv, bqkv, Qh, Kh, Vt);
    k_attn<<<dim3(512), dim3(512), 0, stream>>>(Qh, Kh, Vt, pe_idx, peAll, blank_k,
                                                partial, mlb, lbuf);
    k_comb<<<dim3(8192), dim3(256), 0, stream>>>(partial, mlb, lbuf, blank_v, attnO);
    k_proj<<<dim3(8, 32), dim3(256), 0, stream>>>(attnO, projwb, projb, (float*)d_out);
}